// Round 4
// baseline (79.563 us; speedup 1.0000x reference)
//
#include <hip/hip_runtime.h>

#define NUM_PTS 1024
#define NBATCH 128
#define BT 1024                       // 16 waves per block
#define NW 16
#define R 8                           // rows per lane (64*8 = 512 rows/block)
#define CHAMF_SCALE (1.0f / 1024.0f)
#define KLD_SCALE   (-0.5f * 0.1f / 32.0f)

// ws layout (floats): [256 blocks][1024] col partials | [256] row sums
#define COL_OFF 0
#define RS_OFF  (256 * 1024)

#define ROW_ROR1 0x121                // gfx9 DPP: row rotate by 1 within 16-lane rows

__device__ __forceinline__ float rotr1(float v) {
    return __int_as_float(__builtin_amdgcn_update_dpp(
        0, __float_as_int(v), ROW_ROR1, 0xF, 0xF, true));
}

// R20: rotation moved off the DS pipe. R3 was DS-near-critical (per CU-step:
// 16 waves x (ds_read_b128 12cy + bpermute 6cy) = 285cy vs 320cy VALU/SIMD).
// Now: 16-lane-group scheme - each group sweeps a 16-col window per 16-step
// phase with DPP row_ror:1 (VALU) acc rotation; one ds_bpermute per PHASE
// (4/64 steps) hops the acc set to the next group. DS -> ~193cy (40% slack).
// row_ror direction is probed at runtime (wave-uniform) -> DIR variant.
template <int DIR>   // DIR 0: dpp src = lane+1 (within row); DIR 1: src = lane-1
__device__ __forceinline__ float rot_phases(
    const float4* __restrict__ ringw, int k, int g, int xaddr,
    const float* vx, const float* vy, const float* vz, const float* r2,
    float* m)
{
    float ca = 1e30f;
#pragma unroll 1
    for (int p = 0; p < 4; ++p) {
        const int W = (g + p) & 3;                  // this group's window this phase
        const float4* __restrict__ rw = ringw + (W * 32 + k);
#pragma unroll
        for (int sp = 0; sp < 8; ++sp) {
            const int s0 = 2 * sp;
            const int s1 = s0 + 1;
            const int o0 = (DIR == 0) ? s0 : ((16 - s0) & 15);   // slot offset, imm
            const int o1 = (DIR == 0) ? s1 : ((16 - s1) & 15);
            const float4 qa = rw[o0];
            const float4 qb = rw[o1];
            float da[R], db[R];
#pragma unroll
            for (int r = 0; r < R; ++r)
                da[r] = fmaf(vx[r], qa.x, fmaf(vy[r], qa.y, fmaf(vz[r], qa.z, r2[r] + qa.w)));
            {   // col tree step s0 (4x v_min3)
                const float t0 = fminf(fminf(da[0], da[1]), da[2]);
                const float t1 = fminf(fminf(da[3], da[4]), da[5]);
                const float t2 = fminf(fminf(da[6], da[7]), ca);
                ca = fminf(fminf(t0, t1), t2);
            }
            ca = rotr1(ca);                         // in-row rotate, VALU not DS
#pragma unroll
            for (int r = 0; r < R; ++r)
                db[r] = fmaf(vx[r], qb.x, fmaf(vy[r], qb.y, fmaf(vz[r], qb.z, r2[r] + qb.w)));
#pragma unroll
            for (int r = 0; r < R; ++r)
                m[r] = fminf(fminf(m[r], da[r]), db[r]);         // row fold, v_min3
            {   // col tree step s1
                const float u0 = fminf(fminf(db[0], db[1]), db[2]);
                const float u1 = fminf(fminf(db[3], db[4]), db[5]);
                const float u2 = fminf(fminf(db[6], db[7]), ca);
                ca = fminf(fminf(u0, u1), u2);
            }
            ca = rotr1(ca);
        }
        // phase-boundary: hop acc set to next group (window W -> group that
        // processes it next phase). One bpermute per 16 steps.
        ca = __int_as_float(__builtin_amdgcn_ds_bpermute(xaddr, __float_as_int(ca)));
    }
    return ca;                                      // lane l holds col w*64 + l
}

__global__ __launch_bounds__(BT, 4) void chamfer_shared(
    const float* __restrict__ recon_x,
    const float* __restrict__ x,
    float* __restrict__ ws,
    float* __restrict__ out)
{
    const int bid = blockIdx.x;          // b*2 + rh
    const int b   = bid >> 1;
    const int rh  = bid & 1;
    const int w   = threadIdx.x >> 6;
    const int lt  = threadIdx.x & 63;
    const int t   = threadIdx.x;

    if (bid == 0 && t == 0) out[0] = 0.0f;   // init for colfold2's atomics

    __shared__ float4 ring2[NW][128];        // 32 KB: 4 windows x (16 cols x2 dup)
    __shared__ float  red[NW];

    // --- stage this wave's 64 q cols into 4 doubled 16-col windows
    {
        const float* qsrc = recon_x + (size_t)b * NUM_PTS * 3 + (size_t)(w * 64 + lt) * 3;
        const float qx = qsrc[0], qy = qsrc[1], qz = qsrc[2];
        const float4 q4 = make_float4(qx, qy, qz,
                                      fmaf(qx, qx, fmaf(qy, qy, qz * qz)));
        const int Wl = lt >> 4, jl = lt & 15;
        ring2[w][Wl * 32 + jl]      = q4;
        ring2[w][Wl * 32 + 16 + jl] = q4;    // duplicate: offsets k+o stay < 32
    }

    // --- own 8 contiguous rows (x pts): 6 coalesced float4 loads, keep -2*coord
    const float* rp = x + (size_t)b * NUM_PTS * 3 + (size_t)rh * 512 * 3;
    float vx[R], vy[R], vz[R], r2[R], m[R];
    {
        float buf[24];
        const float4* __restrict__ s4 = (const float4*)(rp + 24 * lt);
        float4* bp = (float4*)buf;
#pragma unroll
        for (int i = 0; i < 6; ++i) bp[i] = s4[i];
#pragma unroll
        for (int k = 0; k < R; ++k) {
            vx[k] = -2.0f * buf[3 * k + 0];
            vy[k] = -2.0f * buf[3 * k + 1];
            vz[k] = -2.0f * buf[3 * k + 2];
            r2[k] = 0.25f * fmaf(vx[k], vx[k], fmaf(vy[k], vy[k], vz[k] * vz[k]));
            m[k]  = 1e30f;
        }
    }

    // --- probe row_ror:1 direction (wave-uniform), run matching variant
    const int k = lt & 15, g = lt >> 4;
    const int xaddr = ((lt + 16) & 63) << 2;
    const int probe = __builtin_amdgcn_update_dpp(0, lt, ROW_ROR1, 0xF, 0xF, true);
    float ca;
    if (probe == ((lt & 48) | ((lt + 1) & 15)))
        ca = rot_phases<0>(&ring2[w][0], k, g, xaddr, vx, vy, vz, r2, m);
    else
        ca = rot_phases<1>(&ring2[w][0], k, g, xaddr, vx, vy, vz, r2, m);

    // --- col partials: lane l holds its own col (w*64 + l)
    ws[COL_OFF + (size_t)bid * 1024 + w * 64 + lt] = ca;

    // --- row-min fold: reuse this wave's (dead, wave-private) ring as combine
    {
        float* mrow = (float*)&ring2[w][0];  // 512 of 2048 B used
#pragma unroll
        for (int kk = 0; kk < R; ++kk)
            mrow[R * lt + kk] = m[kk];
    }
    __syncthreads();

    float v = 0.0f;
    if (t < 512) {
        const float* cb = (const float*)&ring2[0][0];
        v = cb[t];
#pragma unroll
        for (int ww = 1; ww < NW; ++ww)
            v = fminf(v, cb[ww * 512 + t]);
        for (int off = 32; off > 0; off >>= 1)
            v += __shfl_down(v, off, 64);
        if (lt == 0) red[w] = v;
    }
    __syncthreads();
    if (t == 0) {
        float s = 0.f;
#pragma unroll
        for (int ww = 0; ww < 8; ++ww) s += red[ww];
        ws[RS_OFF + bid] = s;
    }
}

// 128 blocks (one per batch): fold the 2 row-half col partials, sum, add row
// sums + this block's 32-latent KLD share, one atomicAdd per block.
__global__ __launch_bounds__(256) void colfold2(
    const float* __restrict__ ws,
    const float* __restrict__ mu,
    const float* __restrict__ logvar,
    float* __restrict__ out)
{
    const int b = blockIdx.x;
    const int t = threadIdx.x;
    const float4* p0 = (const float4*)(ws + COL_OFF + (size_t)(2 * b)     * 1024) + t;
    const float4* p1 = (const float4*)(ws + COL_OFF + (size_t)(2 * b + 1) * 1024) + t;
    const float4 a = *p0;
    const float4 c = *p1;
    float v = (fminf(a.x, c.x) + fminf(a.y, c.y)
             + fminf(a.z, c.z) + fminf(a.w, c.w)) * CHAMF_SCALE;
    if (t < 32) {                             // 128 blocks x 32 = 4096 latents
        const int idx = b * 32 + t;
        const float lv = logvar[idx];
        const float mm = mu[idx];
        v += (1.0f + lv - mm * mm - expf(lv)) * KLD_SCALE;
    }
    for (int off = 32; off > 0; off >>= 1)
        v += __shfl_down(v, off, 64);
    __shared__ float red[4];
    if ((t & 63) == 0) red[t >> 6] = v;
    __syncthreads();
    if (t == 0) {
        float s = red[0] + red[1] + red[2] + red[3];
        s += (ws[RS_OFF + 2 * b] + ws[RS_OFF + 2 * b + 1]) * CHAMF_SCALE;
        atomicAdd(out, s);
    }
}

extern "C" void kernel_launch(void* const* d_in, const int* in_sizes, int n_in,
                              void* d_out, int out_size, void* d_ws, size_t ws_size,
                              hipStream_t stream) {
    const float* recon_x = (const float*)d_in[0];
    const float* x       = (const float*)d_in[1];
    const float* mu      = (const float*)d_in[2];
    const float* logvar  = (const float*)d_in[3];
    float* out = (float*)d_out;
    float* ws  = (float*)d_ws;            // uses ~1.05 MB

    chamfer_shared<<<2 * NBATCH, BT, 0, stream>>>(recon_x, x, ws, out);
    colfold2<<<NBATCH, 256, 0, stream>>>(ws, mu, logvar, out);
}

// Round 5
// 76.813 us; speedup vs baseline: 1.0358x; 1.0358x over previous
//
#include <hip/hip_runtime.h>

#define NUM_PTS 1024
#define NBATCH 128
#define BT 1024                       // 16 waves per block
#define NW 16
#define QW 64                         // q columns per wave (16*64 = all 1024 in-block)
#define R 8                           // rows per lane (64*8 = 512 rows/block)
#define NSTEP 64
#define RING_PAD 132                  // 128 entries + 4 pad (prefetch overrun safe)
#define CHAMF_SCALE (1.0f / 1024.0f)
#define KLD_SCALE   (-0.5f * 0.1f / 32.0f)

// ws layout (floats): [256 blocks][1024] col partials | [256] row sums
#define COL_OFF 0
#define RS_OFF  (256 * 1024)

// R21: revert R20's DPP rotation (regressed +1.8us: row_ror joined BOTH the
// VALU issue stream and the col-acc serial chain, while R3's ds_bpermute
// overlapped off-pipe; DS at 89% was never critical). Chamfer below is R3's
// verified 9.6us loop, byte-identical. Kept from R20 only the tail merge:
// colfold+final fused, one atomicAdd per block, out zero-init in chamfer.
__global__ __launch_bounds__(BT, 4) void chamfer_shared(
    const float* __restrict__ recon_x,
    const float* __restrict__ x,
    float* __restrict__ ws,
    float* __restrict__ out)
{
    const int bid = blockIdx.x;          // b*2 + rh
    const int b   = bid >> 1;
    const int rh  = bid & 1;
    const int w   = threadIdx.x >> 6;
    const int lt  = threadIdx.x & 63;
    const int t   = threadIdx.x;

    if (bid == 0 && t == 0) out[0] = 0.0f;   // init for colfold2's atomics

    __shared__ float4 ring[NW][RING_PAD];   // 33 KB; reused as row-combine after loop
    __shared__ float  red[NW];

    // --- stage this wave's 64 q columns (recon pts), duplicated for wrap-free ring
    {
        const float* qsrc = recon_x + (size_t)b * NUM_PTS * 3 + (size_t)(w * QW + lt) * 3;
        const float qx = qsrc[0], qy = qsrc[1], qz = qsrc[2];
        const float4 q4 = make_float4(qx, qy, qz,
                                      fmaf(qx, qx, fmaf(qy, qy, qz * qz)));
        ring[w][lt]      = q4;
        ring[w][lt + 64] = q4;
    }

    // --- own 8 contiguous rows (x pts): 6 coalesced float4 loads, keep -2*coord
    const float* rp = x + (size_t)b * NUM_PTS * 3 + (size_t)rh * 512 * 3;
    float vx[R], vy[R], vz[R], r2[R], m[R];
    {
        float buf[24];
        const float4* __restrict__ s4 = (const float4*)(rp + 24 * lt);
        float4* bp = (float4*)buf;
#pragma unroll
        for (int i = 0; i < 6; ++i) bp[i] = s4[i];
#pragma unroll
        for (int k = 0; k < R; ++k) {
            vx[k] = -2.0f * buf[3 * k + 0];
            vy[k] = -2.0f * buf[3 * k + 1];
            vz[k] = -2.0f * buf[3 * k + 2];
            r2[k] = 0.25f * fmaf(vx[k], vx[k], fmaf(vy[k], vy[k], vz[k] * vz[k]));
            m[k]  = 1e30f;
        }
    }

    // --- 64 rotation steps, processed in pairs. Wave-private ring: no barrier.
    //     Step s: lane l evals q-col (l+s)&63 of this wave's window; col acc ca
    //     rotates one lane per step (after 64 rotations lane l holds col l).
    const float4* __restrict__ ringw = &ring[w][lt];
    float ca = 1e30f;
    const int rotaddr = ((lt + 1) & 63) << 2;    // new[l] = old[(l+1)&63]
    float4 qA = ringw[0];
    float4 qB = ringw[1];

#pragma unroll 4
    for (int s = 0; s < NSTEP; s += 2) {
        const float4 qC = ringw[s + 2];          // prefetch (pad makes s=62 safe)
        const float4 qD = ringw[s + 3];
        float da[R], db[R];
#pragma unroll
        for (int r = 0; r < R; ++r)
            da[r] = fmaf(vx[r], qA.x, fmaf(vy[r], qA.y, fmaf(vz[r], qA.z, r2[r] + qA.w)));
        {   // col tree step s (4x v_min3)
            const float t0 = fminf(fminf(da[0], da[1]), da[2]);
            const float t1 = fminf(fminf(da[3], da[4]), da[5]);
            const float t2 = fminf(fminf(da[6], da[7]), ca);
            ca = fminf(fminf(t0, t1), t2);
        }
        ca = __int_as_float(__builtin_amdgcn_ds_bpermute(rotaddr, __float_as_int(ca)));
#pragma unroll
        for (int r = 0; r < R; ++r)
            db[r] = fmaf(vx[r], qB.x, fmaf(vy[r], qB.y, fmaf(vz[r], qB.z, r2[r] + qB.w)));
#pragma unroll
        for (int r = 0; r < R; ++r)
            m[r] = fminf(fminf(m[r], da[r]), db[r]);       // v_min3_f32, 0.5/eval
        {   // col tree step s+1
            const float u0 = fminf(fminf(db[0], db[1]), db[2]);
            const float u1 = fminf(fminf(db[3], db[4]), db[5]);
            const float u2 = fminf(fminf(db[6], db[7]), ca);
            ca = fminf(fminf(u0, u1), u2);
        }
        ca = __int_as_float(__builtin_amdgcn_ds_bpermute(rotaddr, __float_as_int(ca)));
        qA = qC;
        qB = qD;
    }

    // --- col partials: lane l holds its own col (w*64 + l)
    ws[COL_OFF + (size_t)bid * 1024 + w * QW + lt] = ca;

    // --- row-min fold: reuse this wave's (dead, wave-private) ring slice as combine
    {
        float* mrow = (float*)&ring[w][0];       // 512 floats needed of 528 available
#pragma unroll
        for (int k = 0; k < R; ++k)
            mrow[R * lt + k] = m[k];
    }
    __syncthreads();

    float v = 0.0f;
    if (t < 512) {                               // waves 0..7, fully active
        const float* cb = (const float*)&ring[0][0];
        v = cb[t];
#pragma unroll
        for (int ww = 1; ww < NW; ++ww)
            v = fminf(v, cb[ww * (RING_PAD * 4) + t]);
        for (int off = 32; off > 0; off >>= 1)
            v += __shfl_down(v, off, 64);
        if (lt == 0) red[w] = v;
    }
    __syncthreads();
    if (t == 0) {
        float s = 0.f;
#pragma unroll
        for (int ww = 0; ww < 8; ++ww) s += red[ww];
        ws[RS_OFF + bid] = s;
    }
}

// 128 blocks (one per batch): fold the 2 row-half col partials, sum, add row
// sums + this block's 32-latent KLD share, one atomicAdd per block.
__global__ __launch_bounds__(256) void colfold2(
    const float* __restrict__ ws,
    const float* __restrict__ mu,
    const float* __restrict__ logvar,
    float* __restrict__ out)
{
    const int b = blockIdx.x;
    const int t = threadIdx.x;
    const float4* p0 = (const float4*)(ws + COL_OFF + (size_t)(2 * b)     * 1024) + t;
    const float4* p1 = (const float4*)(ws + COL_OFF + (size_t)(2 * b + 1) * 1024) + t;
    const float4 a = *p0;
    const float4 c = *p1;
    float v = (fminf(a.x, c.x) + fminf(a.y, c.y)
             + fminf(a.z, c.z) + fminf(a.w, c.w)) * CHAMF_SCALE;
    if (t < 32) {                             // 128 blocks x 32 = 4096 latents
        const int idx = b * 32 + t;
        const float lv = logvar[idx];
        const float mm = mu[idx];
        v += (1.0f + lv - mm * mm - expf(lv)) * KLD_SCALE;
    }
    for (int off = 32; off > 0; off >>= 1)
        v += __shfl_down(v, off, 64);
    __shared__ float red[4];
    if ((t & 63) == 0) red[t >> 6] = v;
    __syncthreads();
    if (t == 0) {
        float s = red[0] + red[1] + red[2] + red[3];
        s += (ws[RS_OFF + 2 * b] + ws[RS_OFF + 2 * b + 1]) * CHAMF_SCALE;
        atomicAdd(out, s);
    }
}

extern "C" void kernel_launch(void* const* d_in, const int* in_sizes, int n_in,
                              void* d_out, int out_size, void* d_ws, size_t ws_size,
                              hipStream_t stream) {
    const float* recon_x = (const float*)d_in[0];
    const float* x       = (const float*)d_in[1];
    const float* mu      = (const float*)d_in[2];
    const float* logvar  = (const float*)d_in[3];
    float* out = (float*)d_out;
    float* ws  = (float*)d_ws;            // uses ~1.05 MB

    chamfer_shared<<<2 * NBATCH, BT, 0, stream>>>(recon_x, x, ws, out);
    colfold2<<<NBATCH, 256, 0, stream>>>(ws, mu, logvar, out);
}